// Round 1
// baseline (795.592 us; speedup 1.0000x reference)
//
#include <hip/hip_runtime.h>
#include <cmath>

// Problem constants (fixed by the reference).
namespace {
constexpr int B_    = 64;
constexpr int DIM_  = 768;
constexpr int HW_   = 56 * 56;      // 3136 (784 float4, row base 16B-aligned)
constexpr int NE_   = 16;
constexpr int K_    = 4;
constexpr int FD_   = 256;
constexpr int ROWS_ = B_ * DIM_;    // 49152
}

// ---------------------------------------------------------------------------
// Kernel A: pooled[b,d] = mean over HW of x[b,d,:,:]. One wave per row.
// 604 MB read -> this is the whole roofline.
// ---------------------------------------------------------------------------
__global__ __launch_bounds__(256) void pool_mean_kernel(const float* __restrict__ x,
                                                        float* __restrict__ pooled) {
    const int wave = threadIdx.x >> 6;
    const int lane = threadIdx.x & 63;
    const int row  = (blockIdx.x << 2) + wave;          // < 49152
    const float4* r4 = reinterpret_cast<const float4*>(x + (size_t)row * HW_);
    float s = 0.0f;
    // 784 float4 per row / 64 lanes = 12 iters + 16-lane tail
    for (int i = lane; i < HW_ / 4; i += 64) {
        float4 v = r4[i];
        s += (v.x + v.y) + (v.z + v.w);
    }
#pragma unroll
    for (int off = 32; off >= 1; off >>= 1) s += __shfl_xor(s, off, 64);
    if (lane == 0) pooled[row] = s * (1.0f / (float)HW_);
}

// ---------------------------------------------------------------------------
// Kernel B: logits[b,e] = dot(pooled[b], gate_w[e]) + dot(freq_emb[b], fgw[e])
// One block per b; 16 lanes per expert; width-16 shuffle reduce.
// ---------------------------------------------------------------------------
__global__ __launch_bounds__(256) void logits_kernel(const float* __restrict__ pooled,
                                                     const float* __restrict__ freq_emb,
                                                     const float* __restrict__ gate_w,
                                                     const float* __restrict__ fgw,
                                                     float* __restrict__ logits) {
    const int b = blockIdx.x;
    const int e = threadIdx.x >> 4;   // 0..15, 16 consecutive lanes share e
    const int l = threadIdx.x & 15;

    const float* pr = pooled   + (size_t)b * DIM_;
    const float* gw = gate_w   + (size_t)e * DIM_;
    const float* fr = freq_emb + (size_t)b * FD_;
    const float* fw = fgw      + (size_t)e * FD_;

    float s = 0.0f;
    for (int i = l; i < DIM_; i += 16) s += pr[i] * gw[i];
    for (int i = l; i < FD_;  i += 16) s += fr[i] * fw[i];
#pragma unroll
    for (int off = 8; off >= 1; off >>= 1) s += __shfl_xor(s, off, 16);
    if (l == 0) logits[b * NE_ + e] = s;
}

// ---------------------------------------------------------------------------
// Kernel C: softmaxes, top-4, gates scatter, aux loss. One 1024-thread block,
// thread t = b*16 + e. 16-lane groups are wave-aligned -> width-16 shuffles.
// ---------------------------------------------------------------------------
__global__ __launch_bounds__(1024) void finalize_kernel(const float* __restrict__ logits_g,
                                                        const float* __restrict__ noise,
                                                        const float* __restrict__ complexity,
                                                        float* __restrict__ out) {
    __shared__ float clean_s[B_][NE_];
    __shared__ float p_s[B_][NE_];
    __shared__ float topv_s[B_][K_];
    __shared__ int   topi_s[B_][K_];
    __shared__ float imp_s[NE_];
    __shared__ float pm_s[NE_];

    const int t = threadIdx.x;        // 0..1023
    const int b = t >> 4;
    const int e = t & 15;
    const float noise_std = 1.0f / (float)NE_;   // 0.0625

    const float logit = logits_g[t];
    const float noisy = logit + noise[t] * noise_std;

    // clean softmax (per-b over 16 experts)
    float m = logit;
#pragma unroll
    for (int off = 8; off >= 1; off >>= 1) m = fmaxf(m, __shfl_xor(m, off, 16));
    float ex = expf(logit - m);
    float s = ex;
#pragma unroll
    for (int off = 8; off >= 1; off >>= 1) s += __shfl_xor(s, off, 16);
    clean_s[b][e] = ex / s;

    // noisy softmax -> gating scores
    float mn = noisy;
#pragma unroll
    for (int off = 8; off >= 1; off >>= 1) mn = fmaxf(mn, __shfl_xor(mn, off, 16));
    float exn = expf(noisy - mn);
    float sn = exn;
#pragma unroll
    for (int off = 8; off >= 1; off >>= 1) sn += __shfl_xor(sn, off, 16);
    const float score = exn / sn;

    // iterative top-4 (jax tie-break: lower index wins on equal values).
    // softmax is monotonic, so indices from scores == indices from noisy logits.
    bool selected = false;
    float thr = 0.0f;
    for (int r = 0; r < K_; ++r) {
        float v = selected ? -1e30f : score;
        int idx = e;
#pragma unroll
        for (int off = 8; off >= 1; off >>= 1) {
            float ov = __shfl_xor(v, off, 16);
            int   oi = __shfl_xor(idx, off, 16);
            if (ov > v || (ov == v && oi < idx)) { v = ov; idx = oi; }
        }
        if (e == 0) { topv_s[b][r] = v; topi_s[b][r] = idx; }
        if (e == idx) selected = true;
        if (r == K_ - 1) thr = __shfl(noisy, idx, 16);  // 4th-largest noisy logit
    }

    // p = 1 - Phi((thr - logit)/noise_std) = 0.5*erfc(nr/sqrt(2))
    const float nr = (thr - logit) * (float)NE_;
    p_s[b][e] = 0.5f * erfcf(nr * 0.70710678118654752f);

    __syncthreads();

    // gates scatter + index/value outputs
    float g = 0.0f;
#pragma unroll
    for (int r = 0; r < K_; ++r)
        if (topi_s[b][r] == e) g = topv_s[b][r];
    out[t] = g;                                           // gates: [0, 1024)
    if (e < K_) {
        out[1024 + b * K_ + e] = (float)topi_s[b][e];     // indices: [1024, 1280)
        out[1280 + b * K_ + e] = topv_s[b][e];            // values:  [1280, 1536)
    }

    // cross-batch reductions for aux loss
    if (t < NE_) {
        float si = 0.0f, sp = 0.0f;
        for (int bb = 0; bb < B_; ++bb) {
            si += clean_s[bb][t];
            sp += p_s[bb][t];
        }
        imp_s[t] = si * complexity[t];
        pm_s[t]  = sp * (1.0f / (float)B_);
    }
    __syncthreads();

    if (t == 0) {
        float mi = 0.0f, mp = 0.0f;
        for (int i = 0; i < NE_; ++i) { mi += imp_s[i]; mp += pm_s[i]; }
        mi *= (1.0f / NE_); mp *= (1.0f / NE_);
        float vi = 0.0f, vp = 0.0f;
        for (int i = 0; i < NE_; ++i) {
            float di = imp_s[i] - mi; vi += di * di;
            float dp = pm_s[i] - mp;  vp += dp * dp;
        }
        const float stdi = sqrtf(vi / (NE_ - 1));
        const float stdp = sqrtf(vp / (NE_ - 1));
        float il = stdi / (mi + 1e-8f); il *= il;
        float ll = stdp / (mp + 1e-8f); ll *= ll;
        out[1536] = 0.5f * il + 0.5f * ll;                // aux_loss
    }
}

// ---------------------------------------------------------------------------
extern "C" void kernel_launch(void* const* d_in, const int* in_sizes, int n_in,
                              void* d_out, int out_size, void* d_ws, size_t ws_size,
                              hipStream_t stream) {
    const float* x          = (const float*)d_in[0];
    const float* freq_emb   = (const float*)d_in[1];
    const float* gate_w     = (const float*)d_in[2];
    const float* fgw        = (const float*)d_in[3];
    const float* complexity = (const float*)d_in[4];
    const float* noise      = (const float*)d_in[5];
    // d_in[6] is k (==4), compile-time constant here.

    float* out    = (float*)d_out;
    float* pooled = (float*)d_ws;            // 49152 floats
    float* logits = pooled + ROWS_;          // 1024 floats

    pool_mean_kernel<<<ROWS_ / 4, 256, 0, stream>>>(x, pooled);
    logits_kernel<<<B_, 256, 0, stream>>>(pooled, freq_emb, gate_w, fgw, logits);
    finalize_kernel<<<1, 1024, 0, stream>>>(logits, noise, complexity, out);
}

// Round 3
// 750.440 us; speedup vs baseline: 1.0602x; 1.0602x over previous
//
#include <hip/hip_runtime.h>
#include <cmath>

// Problem constants (fixed by the reference).
namespace {
constexpr int B_    = 64;
constexpr int DIM_  = 768;
constexpr int HW_   = 56 * 56;      // 3136 floats = 784 float4 per row
constexpr int NE_   = 16;
constexpr int K_    = 4;
constexpr int FD_   = 256;
constexpr int ROWS_ = B_ * DIM_;    // 49152
typedef float v4f __attribute__((ext_vector_type(4)));
}

// ---------------------------------------------------------------------------
// Kernel A: pooled[b,d] = mean over HW of x[b,d,:,:]. One wave per row.
// 604 MB read -> this is the whole roofline. Nontemporal (zero reuse),
// fully unrolled 12 iters (784 = 12*64 + 16) for max outstanding loads.
// ---------------------------------------------------------------------------
__global__ __launch_bounds__(256) void pool_mean_kernel(const float* __restrict__ x,
                                                        float* __restrict__ pooled) {
    const int wave = threadIdx.x >> 6;
    const int lane = threadIdx.x & 63;
    const int row  = (blockIdx.x << 2) + wave;          // < 49152
    const v4f* r4 = reinterpret_cast<const v4f*>(x + (size_t)row * HW_);

    v4f acc = {0.f, 0.f, 0.f, 0.f};
#pragma unroll
    for (int it = 0; it < 12; ++it) {
        v4f v = __builtin_nontemporal_load(r4 + lane + it * 64);
        acc += v;
    }
    if (lane < 16) {
        v4f v = __builtin_nontemporal_load(r4 + 768 + lane);
        acc += v;
    }
    float s = (acc.x + acc.y) + (acc.z + acc.w);
#pragma unroll
    for (int off = 32; off >= 1; off >>= 1) s += __shfl_xor(s, off, 64);
    if (lane == 0) pooled[row] = s * (1.0f / (float)HW_);
}

// ---------------------------------------------------------------------------
// Kernel B: logits[b,e] = dot(pooled[b], gate_w[e]) + dot(freq_emb[b], fgw[e])
// One block per b; 16 lanes per expert; float4 loads; width-16 shuffle reduce.
// ---------------------------------------------------------------------------
__global__ __launch_bounds__(256) void logits_kernel(const float* __restrict__ pooled,
                                                     const float* __restrict__ freq_emb,
                                                     const float* __restrict__ gate_w,
                                                     const float* __restrict__ fgw,
                                                     float* __restrict__ logits) {
    const int b = blockIdx.x;
    const int e = threadIdx.x >> 4;   // 0..15, 16 consecutive lanes share e
    const int l = threadIdx.x & 15;

    const v4f* pr = reinterpret_cast<const v4f*>(pooled   + (size_t)b * DIM_); // 192
    const v4f* gw = reinterpret_cast<const v4f*>(gate_w   + (size_t)e * DIM_);
    const v4f* fr = reinterpret_cast<const v4f*>(freq_emb + (size_t)b * FD_);  // 64
    const v4f* fw = reinterpret_cast<const v4f*>(fgw      + (size_t)e * FD_);

    v4f a = {0.f, 0.f, 0.f, 0.f};
#pragma unroll
    for (int it = 0; it < 12; ++it) a += pr[l + it * 16] * gw[l + it * 16];
#pragma unroll
    for (int it = 0; it < 4;  ++it) a += fr[l + it * 16] * fw[l + it * 16];
    float s = (a.x + a.y) + (a.z + a.w);
#pragma unroll
    for (int off = 8; off >= 1; off >>= 1) s += __shfl_xor(s, off, 16);
    if (l == 0) logits[b * NE_ + e] = s;
}

// ---------------------------------------------------------------------------
// Kernel C: softmaxes, top-4, gates scatter, aux loss. One 1024-thread block,
// thread t = b*16 + e. 16-lane groups are wave-aligned -> width-16 shuffles.
// ---------------------------------------------------------------------------
__global__ __launch_bounds__(1024) void finalize_kernel(const float* __restrict__ logits_g,
                                                        const float* __restrict__ noise,
                                                        const float* __restrict__ complexity,
                                                        float* __restrict__ out) {
    __shared__ float clean_s[B_][NE_];
    __shared__ float p_s[B_][NE_];
    __shared__ float topv_s[B_][K_];
    __shared__ int   topi_s[B_][K_];
    __shared__ float imp_s[NE_];
    __shared__ float pm_s[NE_];

    const int t = threadIdx.x;        // 0..1023
    const int b = t >> 4;
    const int e = t & 15;
    const float noise_std = 1.0f / (float)NE_;   // 0.0625

    const float logit = logits_g[t];
    const float noisy = logit + noise[t] * noise_std;

    // clean softmax (per-b over 16 experts)
    float m = logit;
#pragma unroll
    for (int off = 8; off >= 1; off >>= 1) m = fmaxf(m, __shfl_xor(m, off, 16));
    float ex = expf(logit - m);
    float s = ex;
#pragma unroll
    for (int off = 8; off >= 1; off >>= 1) s += __shfl_xor(s, off, 16);
    clean_s[b][e] = ex / s;

    // noisy softmax -> gating scores
    float mn = noisy;
#pragma unroll
    for (int off = 8; off >= 1; off >>= 1) mn = fmaxf(mn, __shfl_xor(mn, off, 16));
    float exn = expf(noisy - mn);
    float sn = exn;
#pragma unroll
    for (int off = 8; off >= 1; off >>= 1) sn += __shfl_xor(sn, off, 16);
    const float score = exn / sn;

    // iterative top-4 (jax tie-break: lower index wins on equal values).
    // softmax is monotonic, so indices from scores == indices from noisy logits.
    bool selected = false;
    float thr = 0.0f;
    for (int r = 0; r < K_; ++r) {
        float v = selected ? -1e30f : score;
        int idx = e;
#pragma unroll
        for (int off = 8; off >= 1; off >>= 1) {
            float ov = __shfl_xor(v, off, 16);
            int   oi = __shfl_xor(idx, off, 16);
            if (ov > v || (ov == v && oi < idx)) { v = ov; idx = oi; }
        }
        if (e == 0) { topv_s[b][r] = v; topi_s[b][r] = idx; }
        if (e == idx) selected = true;
        if (r == K_ - 1) thr = __shfl(noisy, idx, 16);  // 4th-largest noisy logit
    }

    // p = 1 - Phi((thr - logit)/noise_std) = 0.5*erfc(nr/sqrt(2))
    const float nr = (thr - logit) * (float)NE_;
    p_s[b][e] = 0.5f * erfcf(nr * 0.70710678118654752f);

    __syncthreads();

    // gates scatter + index/value outputs
    float g = 0.0f;
#pragma unroll
    for (int r = 0; r < K_; ++r)
        if (topi_s[b][r] == e) g = topv_s[b][r];
    out[t] = g;                                           // gates: [0, 1024)
    if (e < K_) {
        out[1024 + b * K_ + e] = (float)topi_s[b][e];     // indices: [1024, 1280)
        out[1280 + b * K_ + e] = topv_s[b][e];            // values:  [1280, 1536)
    }

    // cross-batch reductions for aux loss
    if (t < NE_) {
        float si = 0.0f, sp = 0.0f;
        for (int bb = 0; bb < B_; ++bb) {
            si += clean_s[bb][t];
            sp += p_s[bb][t];
        }
        imp_s[t] = si * complexity[t];
        pm_s[t]  = sp * (1.0f / (float)B_);
    }
    __syncthreads();

    if (t == 0) {
        float mi = 0.0f, mp = 0.0f;
        for (int i = 0; i < NE_; ++i) { mi += imp_s[i]; mp += pm_s[i]; }
        mi *= (1.0f / NE_); mp *= (1.0f / NE_);
        float vi = 0.0f, vp = 0.0f;
        for (int i = 0; i < NE_; ++i) {
            float di = imp_s[i] - mi; vi += di * di;
            float dp = pm_s[i] - mp;  vp += dp * dp;
        }
        const float stdi = sqrtf(vi / (NE_ - 1));
        const float stdp = sqrtf(vp / (NE_ - 1));
        float il = stdi / (mi + 1e-8f); il *= il;
        float ll = stdp / (mp + 1e-8f); ll *= ll;
        out[1536] = 0.5f * il + 0.5f * ll;                // aux_loss
    }
}

// ---------------------------------------------------------------------------
extern "C" void kernel_launch(void* const* d_in, const int* in_sizes, int n_in,
                              void* d_out, int out_size, void* d_ws, size_t ws_size,
                              hipStream_t stream) {
    const float* x          = (const float*)d_in[0];
    const float* freq_emb   = (const float*)d_in[1];
    const float* gate_w     = (const float*)d_in[2];
    const float* fgw        = (const float*)d_in[3];
    const float* complexity = (const float*)d_in[4];
    const float* noise      = (const float*)d_in[5];
    // d_in[6] is k (==4), compile-time constant here.

    float* out    = (float*)d_out;
    float* pooled = (float*)d_ws;            // 49152 floats
    float* logits = pooled + ROWS_;          // 1024 floats

    pool_mean_kernel<<<ROWS_ / 4, 256, 0, stream>>>(x, pooled);
    logits_kernel<<<B_, 256, 0, stream>>>(pooled, freq_emb, gate_w, fgw, logits);
    finalize_kernel<<<1, 1024, 0, stream>>>(logits, noise, complexity, out);
}